// Round 14
// baseline (299.253 us; speedup 1.0000x reference)
//
#include <hip/hip_runtime.h>
#include <hip/hip_bf16.h>
#include <math.h>

#define NNODES 50000
#define NEDGES 640000
#define DIM    128
#define PEDIM  37
#define KTOT   165   // DIM + PEDIM
#define KPAD   200   // bf16 B row stride (400 B = 25 int4)
#define PEPAD  64    // PEb row stride (bf16): cols 128..191 of A ([PE|0])
#define HSTR   136   // LDS repack stride (272 B, 16B-aligned)
#define NLAYERS 3
#define NSB    ((NNODES + 255) / 256)   // 196 scan blocks
#define NPEB   ((NNODES * 8 + 255) / 256) // 1563 PEb pack blocks (N*8 int4)
#define NGSC   16                        // BN-stat contention-spread copies
#define NBUCK  ((NNODES + 31) / 32)      // 1563 fill buckets (32 nodes each)
#define FCAP   1280                      // fillB LDS staging capacity (mean 410, sd 20)

using bf16x8 = __attribute__((ext_vector_type(8))) short;
using f32x4  = __attribute__((ext_vector_type(4))) float;
using i32x4  = __attribute__((ext_vector_type(4))) int;

static constexpr size_t alignup(size_t x) { return (x + 255) & ~size_t(255); }
static constexpr size_t OFF_X1   = 0;                                              // bf16 x after layer0 BN
static constexpr size_t OFF_X2   = alignup(OFF_X1  + (size_t)NNODES * DIM * 2);    // bf16 x after layer1 BN
static constexpr size_t OFF_O    = alignup(OFF_X2  + (size_t)NNODES * DIM * 2);    // bf16 agg out
static constexpr size_t OFF_H    = alignup(OFF_O   + (size_t)NNODES * DIM * 2);    // bf16 H
static constexpr size_t OFF_PEB  = alignup(OFF_H   + (size_t)NNODES * DIM * 2);    // bf16 PEb [N][64]
static constexpr size_t OFF_HL   = alignup(OFF_PEB + (size_t)NNODES * PEPAD * 2);
static constexpr size_t OFF_HR   = alignup(OFF_HL  + (size_t)NNODES * 4);
static constexpr size_t OFF_OFFS = alignup(OFF_HR  + (size_t)NNODES * 4);
static constexpr size_t OFF_CUR  = alignup(OFF_OFFS + (size_t)(NNODES + 1) * 4);
static constexpr size_t OFF_CSR  = alignup(OFF_CUR + (size_t)NNODES * 4);
static constexpr size_t OFF_TMP  = alignup(OFF_CSR + (size_t)NEDGES * 4);          // bucketed edge scratch
static constexpr size_t OFF_BCUR = alignup(OFF_TMP + (size_t)NEDGES * 4);          // bucket cursors (64B stride)
static constexpr size_t OFF_BTG  = alignup(OFF_BCUR + (size_t)NBUCK * 64);         // 3 x [128][200] bf16
static constexpr size_t OFF_B2   = alignup(OFF_BTG + 3 * (size_t)DIM * KPAD * 2);
static constexpr size_t OFF_ET   = alignup(OFF_B2  + 3 * DIM * 4);
static constexpr size_t OFF_GS   = alignup(OFF_ET  + 3 * 16 * 4);                  // 2 x NGSC x 256 floats
static constexpr size_t OFF_BS   = alignup(OFF_GS  + 2 * NGSC * 256 * 4);
static constexpr size_t OFF_BP   = alignup(OFF_BS  + 256 * 4);
static constexpr size_t WS_NEED  = alignup(OFF_BP  + 256 * 4);

__device__ inline unsigned short f2b(float f) {
    union { float f; unsigned int u; } x; x.f = f;
    unsigned int r = x.u + 0x7FFFu + ((x.u >> 16) & 1u);
    return (unsigned short)(r >> 16);
}
__device__ inline unsigned int pack2(float a, float b) {
    return (unsigned int)f2b(a) | ((unsigned int)f2b(b) << 16);
}

__device__ inline void gload_lds16(const void* g, void* l) {
    __builtin_amdgcn_global_load_lds((const __attribute__((address_space(1))) void*)g,
                                     (__attribute__((address_space(3))) void*)l, 16, 0, 0);
}

// ---------------- CSR build ----------------

__global__ void k_zero_int(int* __restrict__ p, int n) {
    for (int i = blockIdx.x * blockDim.x + threadIdx.x; i < n; i += gridDim.x * blockDim.x)
        p[i] = 0;
}

__global__ void k_count(const int* __restrict__ dstv, int* __restrict__ cnt) {
    for (int e = blockIdx.x * blockDim.x + threadIdx.x; e < NEDGES; e += gridDim.x * blockDim.x)
        atomicAdd(&cnt[dstv[e]], 1);
}

__global__ __launch_bounds__(256) void k_scan1(const int* __restrict__ cnt, int* __restrict__ bsum) {
    __shared__ int ls[256];
    const int i = blockIdx.x * 256 + threadIdx.x;
    ls[threadIdx.x] = (i < NNODES) ? cnt[i] : 0;
    __syncthreads();
    for (int d = 128; d > 0; d >>= 1) {
        if (threadIdx.x < d) ls[threadIdx.x] += ls[threadIdx.x + d];
        __syncthreads();
    }
    if (threadIdx.x == 0) bsum[blockIdx.x] = ls[0];
}

__global__ __launch_bounds__(256) void k_scan2(const int* __restrict__ bsum,
                                               int* __restrict__ bpre, int* __restrict__ offs) {
    __shared__ int ls[256];
    const int t = threadIdx.x;
    ls[t] = (t < NSB) ? bsum[t] : 0;
    __syncthreads();
    for (int d = 1; d < 256; d <<= 1) {
        int v = (t >= d) ? ls[t - d] : 0;
        __syncthreads();
        ls[t] += v;
        __syncthreads();
    }
    bpre[t] = (t == 0) ? 0 : ls[t - 1];
    if (t == 255) offs[NNODES] = ls[255];
}

// also initializes per-node fallback cursors (cur) and per-bucket cursors (bcur)
__global__ __launch_bounds__(256) void k_scan3(const int* __restrict__ cnt,
                                               const int* __restrict__ bpre,
                                               int* __restrict__ offs, int* __restrict__ cur,
                                               int* __restrict__ bcur) {
    __shared__ int ls[256];
    const int i = blockIdx.x * 256 + threadIdx.x;
    const int v = (i < NNODES) ? cnt[i] : 0;
    ls[threadIdx.x] = v;
    __syncthreads();
    for (int d = 1; d < 256; d <<= 1) {
        int x = (threadIdx.x >= d) ? ls[threadIdx.x - d] : 0;
        __syncthreads();
        ls[threadIdx.x] += x;
        __syncthreads();
    }
    if (i < NNODES) {
        const int excl = ls[threadIdx.x] - v + bpre[blockIdx.x];
        offs[i] = excl;
        cur[i] = excl;
        if ((i & 31) == 0) bcur[(i >> 5) * 16] = excl;   // bucket cursor = region start
    }
}

// phase A: bin edges into 32-node dst-buckets (dense appends at bucket cursors)
__global__ void k_fillA(const int* __restrict__ srcv, const int* __restrict__ dstv,
                        const int* __restrict__ attr, int* __restrict__ bcur,
                        int* __restrict__ tmp) {
    for (int e = blockIdx.x * blockDim.x + threadIdx.x; e < NEDGES; e += gridDim.x * blockDim.x) {
        const int d = dstv[e];
        const int pos = atomicAdd(&bcur[(d >> 5) * 16], 1);
        tmp[pos] = (srcv[e] & 0xFFFF) | (attr[e] << 16) | ((d & 31) << 20);
    }
}

// phase B: per-bucket LDS counting sort -> node-ordered CSR, coalesced write
__global__ __launch_bounds__(256) void k_fillB(const int* __restrict__ offs,
                                               const int* __restrict__ tmp,
                                               int* __restrict__ cur, int* __restrict__ csr) {
    __shared__ int cur32[32];
    __shared__ int sdata[FCAP];
    const int b = blockIdx.x;
    const int nb = b * 32;
    const int nbe = min(nb + 32, NNODES);
    const int start = offs[nb];
    const int end = offs[nbe];
    const int size = end - start;
    if (threadIdx.x < 32) {
        const int node = nb + threadIdx.x;
        cur32[threadIdx.x] = ((node < nbe) ? offs[node] : end) - start;
    }
    __syncthreads();
    if (size <= FCAP) {
        for (int i = threadIdx.x; i < size; i += 256) {
            const int v = tmp[start + i];
            const int p = atomicAdd(&cur32[(v >> 20) & 31], 1);
            sdata[p] = v & 0xFFFFF;
        }
        __syncthreads();
        for (int i = threadIdx.x; i < size; i += 256)
            csr[start + i] = sdata[i];
    } else {   // statistically unreachable fallback
        for (int i = threadIdx.x; i < size; i += 256) {
            const int v = tmp[start + i];
            const int node = nb + ((v >> 20) & 31);
            const int p = atomicAdd(&cur[node], 1);
            csr[p] = v & 0xFFFFF;
        }
    }
}

// ---------------- params body (per layer) ----------------
__device__ inline void params_body(int pb, int tid,
    const float* __restrict__ linW, const float* __restrict__ peW,
    const float* __restrict__ peb, const float* __restrict__ attn_e,
    const float* __restrict__ edge_emb,
    unsigned short* __restrict__ Btg, float* __restrict__ b2, float* __restrict__ et) {
    if (pb < 100) {
        const int idx = pb * 256 + tid;   // 0..25599
        const int j = idx & 127;
        const int k = idx >> 7;           // 0..199
        float v = 0.f;
        if (k < DIM) {
            v = linW[k * DIM + j];
        } else if (k < KTOT) {
            const int p = k - DIM;
            float s = 0.f;
            #pragma unroll 8
            for (int d = 0; d < DIM; ++d) s = fmaf(peW[p * DIM + d], linW[d * DIM + j], s);
            v = s;
        }
        Btg[(size_t)j * KPAD + k] = f2b(v);
    } else {
        if (tid < DIM) {
            float s = 0.f;
            #pragma unroll 8
            for (int d = 0; d < DIM; ++d) s = fmaf(peb[d], linW[d * DIM + tid], s);
            b2[tid] = s;
        } else if (tid < DIM + 9) {
            const int e = tid - DIM;
            float s = 0.f;
            #pragma unroll 8
            for (int d = 0; d < DIM; ++d) s = fmaf(edge_emb[e * DIM + d], attn_e[d], s);
            et[e] = s;
        }
    }
}

// ---------------- one-shot pack: PEb + all 3 layers' params + gs zero ----------------
__global__ __launch_bounds__(256) void k_pack(
    const float* __restrict__ PE,
    const float* __restrict__ lin_W, const float* __restrict__ pe_W,
    const float* __restrict__ pe_b, const float* __restrict__ attn_e,
    const float* __restrict__ edge_emb,
    unsigned short* __restrict__ PEb, unsigned short* __restrict__ Btg,
    float* __restrict__ b2, float* __restrict__ et, float* __restrict__ gs) {
    const int b = blockIdx.x;
    if (b < NPEB) {
        const int idx = b * 256 + threadIdx.x;   // int4 index into PEb
        if (idx >= NNODES * 8) return;
        const int r = idx >> 3, q = idx & 7;      // row, int4-within-row
        float f[8];
        #pragma unroll
        for (int i = 0; i < 8; ++i) {
            const int ci = q * 8 + i;             // PEb col 0..63
            f[i] = (ci < PEDIM) ? PE[(size_t)r * PEDIM + ci] : 0.f;
        }
        i32x4 pk;
        pk.x = (int)pack2(f[0], f[1]); pk.y = (int)pack2(f[2], f[3]);
        pk.z = (int)pack2(f[4], f[5]); pk.w = (int)pack2(f[6], f[7]);
        ((i32x4*)(PEb + (size_t)r * PEPAD))[q] = pk;
    } else if (b < NPEB + 3 * 101) {
        const int pidx = b - NPEB;
        const int l = pidx / 101, pb = pidx % 101;
        params_body(pb, threadIdx.x,
                    lin_W + (size_t)l * DIM * DIM, pe_W + (size_t)l * PEDIM * DIM,
                    pe_b + (size_t)l * DIM, attn_e + (size_t)l * DIM,
                    edge_emb + (size_t)l * 9 * DIM,
                    Btg + (size_t)l * DIM * KPAD, b2 + l * DIM, et + l * 16);
    } else {
        for (int i = threadIdx.x; i < 2 * NGSC * 256; i += 256) gs[i] = 0.f;
    }
}

// ---------------- fused (BN+residual) + MFMA GEMM + hl/hr ----------------
// MODE 0: A-rows from fp32 X. MODE 1: BN(bf16 OPREV) + fp32 XPREV. MODE 2:
// BN(bf16 OPREV) + bf16 XPREV. MODE 1/2 write bf16 XNEXT (nontemporal).
template<int MODE>
__global__ __launch_bounds__(256) void k_gemm(
    const void* __restrict__ OPREV, const void* __restrict__ XPREV,
    const float* __restrict__ gsrc, const float* __restrict__ gamma,
    const float* __restrict__ beta, unsigned short* __restrict__ XNEXT,
    const unsigned short* __restrict__ PEb, const unsigned short* __restrict__ Btg,
    const float* __restrict__ b2, const float* __restrict__ attn_l,
    const float* __restrict__ attn_r,
    unsigned short* __restrict__ H, float* __restrict__ HL, float* __restrict__ HR) {
    __shared__ unsigned short Bls[DIM * KPAD];   // 51.2 KB
    __shared__ float smu[DIM], ssc[DIM], sbt[DIM];
    const int tid = threadIdx.x;
    const int row0 = blockIdx.x * 64;
    const int w = tid >> 6, l = tid & 63;
    const int c = l & 15;     // A-row-in-tile / B-col / D-col
    const int g = l >> 4;     // k-subgroup / D-row-group
    const int row = row0 + w * 16 + c;
    const bool ok = row < NNODES;

    // issue A-source loads early
    f32x4 oxf[4][2], xpf[4][2];
    i32x4 oxb[4], xpb[4];
    #pragma unroll
    for (int s = 0; s < 4; ++s) {
        const int col0 = g * 8 + s * 32;
        const f32x4 z = {0.f, 0.f, 0.f, 0.f};
        const i32x4 zi = {0, 0, 0, 0};
        if (MODE == 0) {
            oxf[s][0] = z; oxf[s][1] = z;
            if (ok) {
                const f32x4* op = (const f32x4*)&((const float*)OPREV)[((size_t)row << 7) + col0];
                oxf[s][0] = op[0]; oxf[s][1] = op[1];
            }
        } else {
            oxb[s] = zi;
            if (ok) oxb[s] = *(const i32x4*)&((const unsigned short*)OPREV)[((size_t)row << 7) + col0];
            if (MODE == 1) {
                xpf[s][0] = z; xpf[s][1] = z;
                if (ok) {
                    const f32x4* xp = (const f32x4*)&((const float*)XPREV)[((size_t)row << 7) + col0];
                    xpf[s][0] = xp[0]; xpf[s][1] = xp[1];
                }
            } else {
                xpb[s] = zi;
                if (ok) xpb[s] = *(const i32x4*)&((const unsigned short*)XPREV)[((size_t)row << 7) + col0];
            }
        }
    }
    i32x4 pe4 = {0, 0, 0, 0}, pe5 = {0, 0, 0, 0};
    if (ok) {
        const i32x4* pp = (const i32x4*)(PEb + (size_t)row * PEPAD);
        pe4 = pp[g];          // cols 128+g*8..+7
        pe5 = pp[4 + g];      // cols 160+g*8..+7
    }

    {   // stage B: 3200 int4, linear
        const int4* gb = (const int4*)Btg;
        int4* lb = (int4*)Bls;
        for (int i = tid; i < 3200; i += 256) gload_lds16(gb + i, lb + i);
    }
    if (MODE != 0 && tid < DIM) {   // block-local BN-stat reduce (16 spread copies)
        float s = 0.f, s2 = 0.f;
        #pragma unroll
        for (int q = 0; q < NGSC; ++q) {
            s += gsrc[q * 256 + tid];
            s2 += gsrc[q * 256 + 128 + tid];
        }
        const float mu = s * (1.f / NNODES);
        const float var = s2 * (1.f / NNODES) - mu * mu;
        smu[tid] = mu;
        ssc[tid] = gamma[tid] * rsqrtf(var + 1e-5f);
        sbt[tid] = beta[tid];
    }
    __syncthreads();

    // build A fragments (and write bf16 XNEXT for MODE 1/2)
    bf16x8 af[6];
    #pragma unroll
    for (int s = 0; s < 4; ++s) {
        const int col0 = g * 8 + s * 32;
        float xn[8];
        if (MODE == 0) {
            xn[0] = oxf[s][0].x; xn[1] = oxf[s][0].y; xn[2] = oxf[s][0].z; xn[3] = oxf[s][0].w;
            xn[4] = oxf[s][1].x; xn[5] = oxf[s][1].y; xn[6] = oxf[s][1].z; xn[7] = oxf[s][1].w;
        } else {
            const unsigned int u0 = (unsigned)oxb[s].x, u1 = (unsigned)oxb[s].y;
            const unsigned int u2 = (unsigned)oxb[s].z, u3 = (unsigned)oxb[s].w;
            float ov[8];
            ov[0] = __uint_as_float(u0 << 16); ov[1] = __uint_as_float(u0 & 0xFFFF0000u);
            ov[2] = __uint_as_float(u1 << 16); ov[3] = __uint_as_float(u1 & 0xFFFF0000u);
            ov[4] = __uint_as_float(u2 << 16); ov[5] = __uint_as_float(u2 & 0xFFFF0000u);
            ov[6] = __uint_as_float(u3 << 16); ov[7] = __uint_as_float(u3 & 0xFFFF0000u);
            float xv[8];
            if (MODE == 1) {
                xv[0] = xpf[s][0].x; xv[1] = xpf[s][0].y; xv[2] = xpf[s][0].z; xv[3] = xpf[s][0].w;
                xv[4] = xpf[s][1].x; xv[5] = xpf[s][1].y; xv[6] = xpf[s][1].z; xv[7] = xpf[s][1].w;
            } else {
                const unsigned int p0 = (unsigned)xpb[s].x, p1 = (unsigned)xpb[s].y;
                const unsigned int p2 = (unsigned)xpb[s].z, p3 = (unsigned)xpb[s].w;
                xv[0] = __uint_as_float(p0 << 16); xv[1] = __uint_as_float(p0 & 0xFFFF0000u);
                xv[2] = __uint_as_float(p1 << 16); xv[3] = __uint_as_float(p1 & 0xFFFF0000u);
                xv[4] = __uint_as_float(p2 << 16); xv[5] = __uint_as_float(p2 & 0xFFFF0000u);
                xv[6] = __uint_as_float(p3 << 16); xv[7] = __uint_as_float(p3 & 0xFFFF0000u);
            }
            const float4 mu0 = *(const float4*)&smu[col0], mu1 = *(const float4*)&smu[col0 + 4];
            const float4 sc0 = *(const float4*)&ssc[col0], sc1 = *(const float4*)&ssc[col0 + 4];
            const float4 bt0 = *(const float4*)&sbt[col0], bt1 = *(const float4*)&sbt[col0 + 4];
            xn[0] = (ov[0] - mu0.x) * sc0.x + bt0.x + xv[0];
            xn[1] = (ov[1] - mu0.y) * sc0.y + bt0.y + xv[1];
            xn[2] = (ov[2] - mu0.z) * sc0.z + bt0.z + xv[2];
            xn[3] = (ov[3] - mu0.w) * sc0.w + bt0.w + xv[3];
            xn[4] = (ov[4] - mu1.x) * sc1.x + bt1.x + xv[4];
            xn[5] = (ov[5] - mu1.y) * sc1.y + bt1.y + xv[5];
            xn[6] = (ov[6] - mu1.z) * sc1.z + bt1.z + xv[6];
            xn[7] = (ov[7] - mu1.w) * sc1.w + bt1.w + xv[7];
        }
        i32x4 pk;
        pk.x = (int)pack2(xn[0], xn[1]); pk.y = (int)pack2(xn[2], xn[3]);
        pk.z = (int)pack2(xn[4], xn[5]); pk.w = (int)pack2(xn[6], xn[7]);
        if (MODE != 0 && ok)
            __builtin_nontemporal_store(pk, (i32x4*)&XNEXT[((size_t)row << 7) + col0]);
        af[s] = *(const bf16x8*)&pk;
    }
    af[4] = *(const bf16x8*)&pe4;
    af[5] = *(const bf16x8*)&pe5;

    f32x4 zero4 = {0.f, 0.f, 0.f, 0.f};
    f32x4 acc[8];
    #pragma unroll
    for (int t = 0; t < 8; ++t) acc[t] = zero4;

    #pragma unroll
    for (int t = 0; t < 8; ++t) {
        const unsigned short* bRow = Bls + (size_t)(t * 16 + c) * KPAD + g * 8;
        #pragma unroll
        for (int s = 0; s < 6; ++s)
            acc[t] = __builtin_amdgcn_mfma_f32_16x16x32_bf16(af[s], *(const bf16x8*)(bRow + s * 32), acc[t], 0, 0, 0);
    }

    float b2v[8], alv[8], arv[8];
    #pragma unroll
    for (int t = 0; t < 8; ++t) {
        b2v[t] = b2[t * 16 + c];
        alv[t] = attn_l[t * 16 + c];
        arv[t] = attn_r[t * 16 + c];
    }
    #pragma unroll
    for (int t = 0; t < 8; ++t)
        #pragma unroll
        for (int j = 0; j < 4; ++j) acc[t][j] += b2v[t];

    #pragma unroll
    for (int j = 0; j < 4; ++j) {
        float sl = 0.f, sr = 0.f;
        #pragma unroll
        for (int t = 0; t < 8; ++t) { sl = fmaf(acc[t][j], alv[t], sl); sr = fmaf(acc[t][j], arv[t], sr); }
        #pragma unroll
        for (int m = 1; m < 16; m <<= 1) {
            sl += __shfl_xor(sl, m, 64);
            sr += __shfl_xor(sr, m, 64);
        }
        const int grow = row0 + w * 16 + g * 4 + j;
        if (grow < NNODES && c == 0) { HL[grow] = sl; HR[grow] = sr; }
    }

    // repack D tile -> bf16 via LDS (reuse Bls), then coalesced store
    __syncthreads();
    unsigned short* Hls = Bls;
    #pragma unroll
    for (int t = 0; t < 8; ++t)
        #pragma unroll
        for (int j = 0; j < 4; ++j)
            Hls[(w * 16 + g * 4 + j) * HSTR + t * 16 + c] = f2b(acc[t][j]);
    __syncthreads();
    #pragma unroll
    for (int kb = 0; kb < 4; ++kb) {
        const int idx = tid + kb * 256;         // 0..1023
        const int r = idx >> 4, kc = idx & 15;
        const int grow = row0 + r;
        if (grow < NNODES) {
            const int4 v = *(const int4*)(Hls + r * HSTR + kc * 8);
            ((int4*)(H + ((size_t)grow << 7)))[kc] = v;
        }
    }
}

// ---------------- per-node softmax + aggregation (one wave per node) ----------------
// 4 edge-groups x 16 lanes (lane owns 8 cols); 4-slot unroll = 16 edges/iter.
// Streaming traffic (csr loads, OUT stores) is nontemporal to keep H in L2.
// FINAL=0: OUT(bf16) = agg + bias. FINAL=1: OUT(fp32 d_out) = agg + bias + bf16 xprev.
template<int FINAL>
__global__ __launch_bounds__(256) void k_agg(
    const int* __restrict__ offs, const int* __restrict__ csr,
    const float* __restrict__ HL, const float* __restrict__ HR,
    const float* __restrict__ et, const unsigned short* __restrict__ H,
    const float* __restrict__ bias, const unsigned short* __restrict__ xprev,
    void* __restrict__ OUTv) {
    const int lane = threadIdx.x & 63;
    const int node = blockIdx.x * 4 + (threadIdx.x >> 6);   // grid exact
    const int off0 = offs[node];
    const int deg = offs[node + 1] - off0;

    const float hri = HR[node];
    float myA = 0.f;
    int myE = 0;          // init 0 -> invalid slots broadcast a safe, valid row id
    float mx = -1e30f;
    for (int j = lane; j < deg; j += 64) {
        const int en = __builtin_nontemporal_load(&csr[off0 + j]);
        float al = HL[en & 0xFFFF] + hri + et[en >> 16];
        al = al > 0.f ? al : 0.2f * al;
        if (j < 64) { myA = al; myE = en & 0xFFFF; }
        mx = fmaxf(mx, al);
    }
    #pragma unroll
    for (int m = 1; m < 64; m <<= 1) mx = fmaxf(mx, __shfl_xor(mx, m, 64));

    float s = 0.f, wv = 0.f;
    const bool small = deg <= 64;
    if (small) {
        wv = (lane < deg) ? __expf(myA - mx) : 0.f;
        s = wv;
    } else {
        for (int j = lane; j < deg; j += 64) {
            const int en = csr[off0 + j];
            float al = HL[en & 0xFFFF] + hri + et[en >> 16];
            al = al > 0.f ? al : 0.2f * al;
            s += __expf(al - mx);
        }
    }
    #pragma unroll
    for (int m = 1; m < 64; m <<= 1) s += __shfl_xor(s, m, 64);
    const float invd = (deg > 0) ? 1.f / s : 0.f;
    wv *= invd;

    const int eg = lane >> 4, c = lane & 15;   // group 0..3, col chunk: cols c*8..c*8+7
    float a[8];
    #pragma unroll
    for (int t = 0; t < 8; ++t) a[t] = 0.f;

    if (small) {
        for (int jb = 0; jb < deg; jb += 16) {
            float wl[4];
            int sl[4];
            #pragma unroll
            for (int u = 0; u < 4; ++u) {
                const int j = jb + eg + u * 4;
                wl[u] = __shfl(wv, j & 63, 64);
                sl[u] = __shfl(myE, j & 63, 64);
                if (j >= deg) wl[u] = 0.f;
            }
            int4 hv0 = *(const int4*)(H + ((size_t)sl[0] << 7) + (c << 3));
            int4 hv1 = *(const int4*)(H + ((size_t)sl[1] << 7) + (c << 3));
            int4 hv2 = *(const int4*)(H + ((size_t)sl[2] << 7) + (c << 3));
            int4 hv3 = *(const int4*)(H + ((size_t)sl[3] << 7) + (c << 3));
            const int4 hvv[4] = {hv0, hv1, hv2, hv3};
            #pragma unroll
            for (int u = 0; u < 4; ++u) {
                const unsigned int ux = (unsigned)hvv[u].x, uy = (unsigned)hvv[u].y;
                const unsigned int uz = (unsigned)hvv[u].z, uw = (unsigned)hvv[u].w;
                const float wg = wl[u];
                a[0] = fmaf(wg, __uint_as_float(ux << 16), a[0]);
                a[1] = fmaf(wg, __uint_as_float(ux & 0xFFFF0000u), a[1]);
                a[2] = fmaf(wg, __uint_as_float(uy << 16), a[2]);
                a[3] = fmaf(wg, __uint_as_float(uy & 0xFFFF0000u), a[3]);
                a[4] = fmaf(wg, __uint_as_float(uz << 16), a[4]);
                a[5] = fmaf(wg, __uint_as_float(uz & 0xFFFF0000u), a[5]);
                a[6] = fmaf(wg, __uint_as_float(uw << 16), a[6]);
                a[7] = fmaf(wg, __uint_as_float(uw & 0xFFFF0000u), a[7]);
            }
        }
    } else {
        for (int jb = 0; jb < deg; jb += 8) {
            float wl[2];
            int sl[2];
            #pragma unroll
            for (int u = 0; u < 2; ++u) {
                const int j = jb + eg + u * 4;
                wl[u] = 0.f; sl[u] = 0;
                if (j < deg) {
                    const int en = csr[off0 + j];
                    sl[u] = en & 0xFFFF;
                    float al = HL[sl[u]] + hri + et[en >> 16];
                    al = al > 0.f ? al : 0.2f * al;
                    wl[u] = __expf(al - mx) * invd;
                }
            }
            int4 hv0 = *(const int4*)(H + ((size_t)sl[0] << 7) + (c << 3));
            int4 hv1 = *(const int4*)(H + ((size_t)sl[1] << 7) + (c << 3));
            const int4 hvv[2] = {hv0, hv1};
            #pragma unroll
            for (int u = 0; u < 2; ++u) {
                const unsigned int ux = (unsigned)hvv[u].x, uy = (unsigned)hvv[u].y;
                const unsigned int uz = (unsigned)hvv[u].z, uw = (unsigned)hvv[u].w;
                const float wg = wl[u];
                a[0] = fmaf(wg, __uint_as_float(ux << 16), a[0]);
                a[1] = fmaf(wg, __uint_as_float(ux & 0xFFFF0000u), a[1]);
                a[2] = fmaf(wg, __uint_as_float(uy << 16), a[2]);
                a[3] = fmaf(wg, __uint_as_float(uy & 0xFFFF0000u), a[3]);
                a[4] = fmaf(wg, __uint_as_float(uz << 16), a[4]);
                a[5] = fmaf(wg, __uint_as_float(uz & 0xFFFF0000u), a[5]);
                a[6] = fmaf(wg, __uint_as_float(uw << 16), a[6]);
                a[7] = fmaf(wg, __uint_as_float(uw & 0xFFFF0000u), a[7]);
            }
        }
    }

    // cross-group reduce: 2 levels (bits 4,5)
    #pragma unroll
    for (int m = 16; m < 64; m <<= 1)
        #pragma unroll
        for (int t = 0; t < 8; ++t) a[t] += __shfl_xor(a[t], m, 64);

    if (eg == 0) {
        float o[8];
        const float* bp = bias + (c << 3);
        #pragma unroll
        for (int t = 0; t < 8; ++t) o[t] = a[t] + bp[t];
        if (FINAL) {
            float* OUT = (float*)OUTv;
            const int4 xb = *(const int4*)(xprev + ((size_t)node << 7) + (c << 3));
            const unsigned int p0 = (unsigned)xb.x, p1 = (unsigned)xb.y;
            const unsigned int p2 = (unsigned)xb.z, p3 = (unsigned)xb.w;
            o[0] += __uint_as_float(p0 << 16); o[1] += __uint_as_float(p0 & 0xFFFF0000u);
            o[2] += __uint_as_float(p1 << 16); o[3] += __uint_as_float(p1 & 0xFFFF0000u);
            o[4] += __uint_as_float(p2 << 16); o[5] += __uint_as_float(p2 & 0xFFFF0000u);
            o[6] += __uint_as_float(p3 << 16); o[7] += __uint_as_float(p3 & 0xFFFF0000u);
            float* op = OUT + ((size_t)node << 7) + (c << 3);
            f32x4 o0 = {o[0], o[1], o[2], o[3]};
            f32x4 o1 = {o[4], o[5], o[6], o[7]};
            __builtin_nontemporal_store(o0, (f32x4*)op);
            __builtin_nontemporal_store(o1, (f32x4*)(op + 4));
        } else {
            unsigned short* OUT = (unsigned short*)OUTv;
            i32x4 pk;
            pk.x = (int)pack2(o[0], o[1]); pk.y = (int)pack2(o[2], o[3]);
            pk.z = (int)pack2(o[4], o[5]); pk.w = (int)pack2(o[6], o[7]);
            __builtin_nontemporal_store(pk, (i32x4*)(OUT + ((size_t)node << 7) + (c << 3)));
        }
    }
}

// ---------------- BN stats on bf16 obuf (196 blocks, 16-copy spread gs) ----------------
__global__ __launch_bounds__(256) void k_bnstats(
    const unsigned short* __restrict__ OUT, float* __restrict__ gs) {
    __shared__ float lsl[256], lsh[256], l2l[256], l2h[256];
    const int c2 = threadIdx.x & 63;   // uint col = bf16 cols {2c2, 2c2+1}
    const int q  = threadIdx.x >> 6;   // 0..3 row split
    const int rend = min(NNODES, (int)(blockIdx.x * 256 + 256));
    const unsigned int* U = (const unsigned int*)OUT;
    float sl = 0.f, sh = 0.f, s2l = 0.f, s2h = 0.f;
    for (int r = blockIdx.x * 256 + q; r < rend; r += 4) {
        const unsigned int u = __builtin_nontemporal_load(&U[(size_t)r * 64 + c2]);
        const float lo = __uint_as_float(u << 16);
        const float hi = __uint_as_float(u & 0xFFFF0000u);
        sl += lo; sh += hi;
        s2l = fmaf(lo, lo, s2l); s2h = fmaf(hi, hi, s2h);
    }
    lsl[threadIdx.x] = sl; lsh[threadIdx.x] = sh;
    l2l[threadIdx.x] = s2l; l2h[threadIdx.x] = s2h;
    __syncthreads();
    if (threadIdx.x < 64) {
        float a0 = 0.f, a1 = 0.f, a2 = 0.f, a3 = 0.f;
        #pragma unroll
        for (int k = 0; k < 4; ++k) {
            a0 += lsl[k * 64 + c2]; a1 += lsh[k * 64 + c2];
            a2 += l2l[k * 64 + c2]; a3 += l2h[k * 64 + c2];
        }
        const int qq = blockIdx.x & (NGSC - 1);
        atomicAdd(&gs[qq * 256 + 2 * c2], a0);
        atomicAdd(&gs[qq * 256 + 2 * c2 + 1], a1);
        atomicAdd(&gs[qq * 256 + 128 + 2 * c2], a2);
        atomicAdd(&gs[qq * 256 + 128 + 2 * c2 + 1], a3);
    }
}

// ---------------- host ----------------
extern "C" void kernel_launch(void* const* d_in, const int* in_sizes, int n_in,
                              void* d_out, int out_size, void* d_ws, size_t ws_size,
                              hipStream_t stream) {
    const float* X_n      = (const float*)d_in[0];
    const float* PE       = (const float*)d_in[1];
    const int*   eidx     = (const int*)d_in[2];
    const int*   eattr    = (const int*)d_in[3];
    const float* edge_emb = (const float*)d_in[4];
    const float* pe_W     = (const float*)d_in[5];
    const float* pe_b     = (const float*)d_in[6];
    const float* lin_W    = (const float*)d_in[7];
    const float* attn_l   = (const float*)d_in[8];
    const float* attn_r   = (const float*)d_in[9];
    const float* attn_e   = (const float*)d_in[10];
    const float* bias     = (const float*)d_in[11];
    const float* bng      = (const float*)d_in[12];
    const float* bnb      = (const float*)d_in[13];

    if (ws_size < WS_NEED) return;

    char* ws = (char*)d_ws;
    unsigned short* x1    = (unsigned short*)(ws + OFF_X1);
    unsigned short* x2    = (unsigned short*)(ws + OFF_X2);
    unsigned short* obufb = (unsigned short*)(ws + OFF_O);
    unsigned short* hbuf  = (unsigned short*)(ws + OFF_H);
    unsigned short* PEb   = (unsigned short*)(ws + OFF_PEB);
    float* hl     = (float*)(ws + OFF_HL);
    float* hr     = (float*)(ws + OFF_HR);
    int*   offs   = (int*)(ws + OFF_OFFS);
    int*   cur    = (int*)(ws + OFF_CUR);
    int*   csr    = (int*)(ws + OFF_CSR);
    int*   tmp    = (int*)(ws + OFF_TMP);
    int*   bcur   = (int*)(ws + OFF_BCUR);
    unsigned short* Btg = (unsigned short*)(ws + OFF_BTG);
    float* b2     = (float*)(ws + OFF_B2);
    float* et     = (float*)(ws + OFF_ET);
    float* gs     = (float*)(ws + OFF_GS);   // gs + NGSC*256*b for boundary b
    int*   bsum   = (int*)(ws + OFF_BS);
    int*   bpre   = (int*)(ws + OFF_BP);

    const int* srcv = eidx;
    const int* dstv = eidx + NEDGES;

    hipLaunchKernelGGL(k_zero_int, dim3(256), dim3(256), 0, stream, cur, NNODES);
    hipLaunchKernelGGL(k_count, dim3(1024), dim3(256), 0, stream, dstv, cur);
    hipLaunchKernelGGL(k_scan1, dim3(NSB), dim3(256), 0, stream, cur, bsum);
    hipLaunchKernelGGL(k_scan2, dim3(1), dim3(256), 0, stream, bsum, bpre, offs);
    hipLaunchKernelGGL(k_scan3, dim3(NSB), dim3(256), 0, stream, cur, bpre, offs, cur, bcur);
    hipLaunchKernelGGL(k_fillA, dim3(1024), dim3(256), 0, stream, srcv, dstv, eattr, bcur, tmp);
    hipLaunchKernelGGL(k_fillB, dim3(NBUCK), dim3(256), 0, stream, offs, tmp, cur, csr);
    hipLaunchKernelGGL(k_pack, dim3(NPEB + 3 * 101 + 1), dim3(256), 0, stream,
                       PE, lin_W, pe_W, pe_b, attn_e, edge_emb, PEb, Btg, b2, et, gs);

    const int NGB = (NNODES + 63) / 64;
    // layer 0
    hipLaunchKernelGGL((k_gemm<0>), dim3(NGB), dim3(256), 0, stream,
                       (const void*)X_n, (const void*)nullptr, (const float*)nullptr,
                       (const float*)nullptr, (const float*)nullptr, (unsigned short*)nullptr,
                       PEb, Btg, b2, attn_l, attn_r, hbuf, hl, hr);
    hipLaunchKernelGGL((k_agg<0>), dim3(NNODES / 4), dim3(256), 0, stream,
                       offs, csr, hl, hr, et, hbuf, bias, (const unsigned short*)nullptr, (void*)obufb);
    hipLaunchKernelGGL(k_bnstats, dim3(NSB), dim3(256), 0, stream, obufb, gs);
    // layer 1 (BN boundary 0 fused into GEMM; residual source = fp32 X_n)
    hipLaunchKernelGGL((k_gemm<1>), dim3(NGB), dim3(256), 0, stream,
                       (const void*)obufb, (const void*)X_n, gs, bng, bnb, x1,
                       PEb, Btg + (size_t)DIM * KPAD, b2 + DIM, attn_l + DIM, attn_r + DIM,
                       hbuf, hl, hr);
    hipLaunchKernelGGL((k_agg<0>), dim3(NNODES / 4), dim3(256), 0, stream,
                       offs, csr, hl, hr, et + 16, hbuf, bias + DIM, (const unsigned short*)nullptr, (void*)obufb);
    hipLaunchKernelGGL(k_bnstats, dim3(NSB), dim3(256), 0, stream, obufb, gs + NGSC * 256);
    // layer 2 (BN boundary 1 fused into GEMM; residual source = bf16 x1)
    hipLaunchKernelGGL((k_gemm<2>), dim3(NGB), dim3(256), 0, stream,
                       (const void*)obufb, (const void*)x1, gs + NGSC * 256, bng + DIM, bnb + DIM, x2,
                       PEb, Btg + 2 * (size_t)DIM * KPAD, b2 + 2 * DIM, attn_l + 2 * DIM, attn_r + 2 * DIM,
                       hbuf, hl, hr);
    hipLaunchKernelGGL((k_agg<1>), dim3(NNODES / 4), dim3(256), 0, stream,
                       offs, csr, hl, hr, et + 32, hbuf, bias + 2 * DIM, x2,
                       (void*)d_out);
}

// Round 15
// 271.016 us; speedup vs baseline: 1.1042x; 1.1042x over previous
//
#include <hip/hip_runtime.h>
#include <hip/hip_bf16.h>
#include <math.h>

#define NNODES 50000
#define NEDGES 640000
#define DIM    128
#define PEDIM  37
#define KTOT   165   // DIM + PEDIM
#define KPAD   200   // bf16 B row stride (400 B = 25 int4)
#define PEPAD  64    // PEb row stride (bf16): cols 128..191 of A ([PE|0])
#define HSTR   136   // LDS repack stride (272 B, 16B-aligned)
#define NLAYERS 3
#define NSB    ((NNODES + 255) / 256)   // 196 scan blocks
#define NPEB   ((NNODES * 8 + 255) / 256) // 1563 PEb pack blocks (N*8 int4)
#define NGSC   16                        // BN-stat contention-spread copies
#define NBUCK  ((NNODES + 31) / 32)      // 1563 fill buckets (32 nodes each)
#define FCAP   1280                      // fillB LDS staging capacity (mean 410, sd 20)

using bf16x8 = __attribute__((ext_vector_type(8))) short;
using f32x4  = __attribute__((ext_vector_type(4))) float;
using i32x4  = __attribute__((ext_vector_type(4))) int;

static constexpr size_t alignup(size_t x) { return (x + 255) & ~size_t(255); }
static constexpr size_t OFF_X1   = 0;                                              // bf16 x after layer0 BN
static constexpr size_t OFF_X2   = alignup(OFF_X1  + (size_t)NNODES * DIM * 2);    // bf16 x after layer1 BN
static constexpr size_t OFF_O    = alignup(OFF_X2  + (size_t)NNODES * DIM * 2);    // bf16 agg out
static constexpr size_t OFF_H    = alignup(OFF_O   + (size_t)NNODES * DIM * 2);    // bf16 H
static constexpr size_t OFF_PEB  = alignup(OFF_H   + (size_t)NNODES * DIM * 2);    // bf16 PEb [N][64]
static constexpr size_t OFF_HL   = alignup(OFF_PEB + (size_t)NNODES * PEPAD * 2);
static constexpr size_t OFF_HR   = alignup(OFF_HL  + (size_t)NNODES * 4);
static constexpr size_t OFF_OFFS = alignup(OFF_HR  + (size_t)NNODES * 4);
static constexpr size_t OFF_CUR  = alignup(OFF_OFFS + (size_t)(NNODES + 1) * 4);
static constexpr size_t OFF_CSR  = alignup(OFF_CUR + (size_t)NNODES * 4);
static constexpr size_t OFF_TMP  = alignup(OFF_CSR + (size_t)NEDGES * 4);          // bucketed edge scratch
static constexpr size_t OFF_BCUR = alignup(OFF_TMP + (size_t)NEDGES * 4);          // bucket cursors (64B stride)
static constexpr size_t OFF_BTG  = alignup(OFF_BCUR + (size_t)NBUCK * 64);         // 3 x [128][200] bf16
static constexpr size_t OFF_B2   = alignup(OFF_BTG + 3 * (size_t)DIM * KPAD * 2);
static constexpr size_t OFF_ET   = alignup(OFF_B2  + 3 * DIM * 4);
static constexpr size_t OFF_GS   = alignup(OFF_ET  + 3 * 16 * 4);                  // 2 x NGSC x 256 floats
static constexpr size_t OFF_BS   = alignup(OFF_GS  + 2 * NGSC * 256 * 4);
static constexpr size_t OFF_BP   = alignup(OFF_BS  + 256 * 4);
static constexpr size_t WS_NEED  = alignup(OFF_BP  + 256 * 4);

__device__ inline unsigned short f2b(float f) {
    union { float f; unsigned int u; } x; x.f = f;
    unsigned int r = x.u + 0x7FFFu + ((x.u >> 16) & 1u);
    return (unsigned short)(r >> 16);
}
__device__ inline unsigned int pack2(float a, float b) {
    return (unsigned int)f2b(a) | ((unsigned int)f2b(b) << 16);
}

__device__ inline void gload_lds16(const void* g, void* l) {
    __builtin_amdgcn_global_load_lds((const __attribute__((address_space(1))) void*)g,
                                     (__attribute__((address_space(3))) void*)l, 16, 0, 0);
}

// ---------------- CSR build ----------------

__global__ void k_zero_int(int* __restrict__ p, int n) {
    for (int i = blockIdx.x * blockDim.x + threadIdx.x; i < n; i += gridDim.x * blockDim.x)
        p[i] = 0;
}

__global__ void k_count(const int* __restrict__ dstv, int* __restrict__ cnt) {
    for (int e = blockIdx.x * blockDim.x + threadIdx.x; e < NEDGES; e += gridDim.x * blockDim.x)
        atomicAdd(&cnt[dstv[e]], 1);
}

__global__ __launch_bounds__(256) void k_scan1(const int* __restrict__ cnt, int* __restrict__ bsum) {
    __shared__ int ls[256];
    const int i = blockIdx.x * 256 + threadIdx.x;
    ls[threadIdx.x] = (i < NNODES) ? cnt[i] : 0;
    __syncthreads();
    for (int d = 128; d > 0; d >>= 1) {
        if (threadIdx.x < d) ls[threadIdx.x] += ls[threadIdx.x + d];
        __syncthreads();
    }
    if (threadIdx.x == 0) bsum[blockIdx.x] = ls[0];
}

__global__ __launch_bounds__(256) void k_scan2(const int* __restrict__ bsum,
                                               int* __restrict__ bpre, int* __restrict__ offs) {
    __shared__ int ls[256];
    const int t = threadIdx.x;
    ls[t] = (t < NSB) ? bsum[t] : 0;
    __syncthreads();
    for (int d = 1; d < 256; d <<= 1) {
        int v = (t >= d) ? ls[t - d] : 0;
        __syncthreads();
        ls[t] += v;
        __syncthreads();
    }
    bpre[t] = (t == 0) ? 0 : ls[t - 1];
    if (t == 255) offs[NNODES] = ls[255];
}

// also initializes per-node fallback cursors (cur) and per-bucket cursors (bcur)
__global__ __launch_bounds__(256) void k_scan3(const int* __restrict__ cnt,
                                               const int* __restrict__ bpre,
                                               int* __restrict__ offs, int* __restrict__ cur,
                                               int* __restrict__ bcur) {
    __shared__ int ls[256];
    const int i = blockIdx.x * 256 + threadIdx.x;
    const int v = (i < NNODES) ? cnt[i] : 0;
    ls[threadIdx.x] = v;
    __syncthreads();
    for (int d = 1; d < 256; d <<= 1) {
        int x = (threadIdx.x >= d) ? ls[threadIdx.x - d] : 0;
        __syncthreads();
        ls[threadIdx.x] += x;
        __syncthreads();
    }
    if (i < NNODES) {
        const int excl = ls[threadIdx.x] - v + bpre[blockIdx.x];
        offs[i] = excl;
        cur[i] = excl;
        if ((i & 31) == 0) bcur[(i >> 5) * 16] = excl;   // bucket cursor = region start
    }
}

// phase A: bin edges into 32-node dst-buckets (dense appends at bucket cursors)
__global__ void k_fillA(const int* __restrict__ srcv, const int* __restrict__ dstv,
                        const int* __restrict__ attr, int* __restrict__ bcur,
                        int* __restrict__ tmp) {
    for (int e = blockIdx.x * blockDim.x + threadIdx.x; e < NEDGES; e += gridDim.x * blockDim.x) {
        const int d = dstv[e];
        const int pos = atomicAdd(&bcur[(d >> 5) * 16], 1);
        tmp[pos] = (srcv[e] & 0xFFFF) | (attr[e] << 16) | ((d & 31) << 20);
    }
}

// phase B: per-bucket LDS counting sort -> node-ordered CSR, coalesced write
__global__ __launch_bounds__(256) void k_fillB(const int* __restrict__ offs,
                                               const int* __restrict__ tmp,
                                               int* __restrict__ cur, int* __restrict__ csr) {
    __shared__ int cur32[32];
    __shared__ int sdata[FCAP];
    const int b = blockIdx.x;
    const int nb = b * 32;
    const int nbe = min(nb + 32, NNODES);
    const int start = offs[nb];
    const int end = offs[nbe];
    const int size = end - start;
    if (threadIdx.x < 32) {
        const int node = nb + threadIdx.x;
        cur32[threadIdx.x] = ((node < nbe) ? offs[node] : end) - start;
    }
    __syncthreads();
    if (size <= FCAP) {
        for (int i = threadIdx.x; i < size; i += 256) {
            const int v = tmp[start + i];
            const int p = atomicAdd(&cur32[(v >> 20) & 31], 1);
            sdata[p] = v & 0xFFFFF;
        }
        __syncthreads();
        for (int i = threadIdx.x; i < size; i += 256)
            csr[start + i] = sdata[i];
    } else {   // statistically unreachable fallback
        for (int i = threadIdx.x; i < size; i += 256) {
            const int v = tmp[start + i];
            const int node = nb + ((v >> 20) & 31);
            const int p = atomicAdd(&cur[node], 1);
            csr[p] = v & 0xFFFFF;
        }
    }
}

// ---------------- params body (per layer) ----------------
__device__ inline void params_body(int pb, int tid,
    const float* __restrict__ linW, const float* __restrict__ peW,
    const float* __restrict__ peb, const float* __restrict__ attn_e,
    const float* __restrict__ edge_emb,
    unsigned short* __restrict__ Btg, float* __restrict__ b2, float* __restrict__ et) {
    if (pb < 100) {
        const int idx = pb * 256 + tid;   // 0..25599
        const int j = idx & 127;
        const int k = idx >> 7;           // 0..199
        float v = 0.f;
        if (k < DIM) {
            v = linW[k * DIM + j];
        } else if (k < KTOT) {
            const int p = k - DIM;
            float s = 0.f;
            #pragma unroll 8
            for (int d = 0; d < DIM; ++d) s = fmaf(peW[p * DIM + d], linW[d * DIM + j], s);
            v = s;
        }
        Btg[(size_t)j * KPAD + k] = f2b(v);
    } else {
        if (tid < DIM) {
            float s = 0.f;
            #pragma unroll 8
            for (int d = 0; d < DIM; ++d) s = fmaf(peb[d], linW[d * DIM + tid], s);
            b2[tid] = s;
        } else if (tid < DIM + 9) {
            const int e = tid - DIM;
            float s = 0.f;
            #pragma unroll 8
            for (int d = 0; d < DIM; ++d) s = fmaf(edge_emb[e * DIM + d], attn_e[d], s);
            et[e] = s;
        }
    }
}

// ---------------- one-shot pack: PEb + all 3 layers' params + gs zero ----------------
__global__ __launch_bounds__(256) void k_pack(
    const float* __restrict__ PE,
    const float* __restrict__ lin_W, const float* __restrict__ pe_W,
    const float* __restrict__ pe_b, const float* __restrict__ attn_e,
    const float* __restrict__ edge_emb,
    unsigned short* __restrict__ PEb, unsigned short* __restrict__ Btg,
    float* __restrict__ b2, float* __restrict__ et, float* __restrict__ gs) {
    const int b = blockIdx.x;
    if (b < NPEB) {
        const int idx = b * 256 + threadIdx.x;   // int4 index into PEb
        if (idx >= NNODES * 8) return;
        const int r = idx >> 3, q = idx & 7;      // row, int4-within-row
        float f[8];
        #pragma unroll
        for (int i = 0; i < 8; ++i) {
            const int ci = q * 8 + i;             // PEb col 0..63
            f[i] = (ci < PEDIM) ? PE[(size_t)r * PEDIM + ci] : 0.f;
        }
        int4 pk;
        pk.x = (int)pack2(f[0], f[1]); pk.y = (int)pack2(f[2], f[3]);
        pk.z = (int)pack2(f[4], f[5]); pk.w = (int)pack2(f[6], f[7]);
        ((int4*)(PEb + (size_t)r * PEPAD))[q] = pk;
    } else if (b < NPEB + 3 * 101) {
        const int pidx = b - NPEB;
        const int l = pidx / 101, pb = pidx % 101;
        params_body(pb, threadIdx.x,
                    lin_W + (size_t)l * DIM * DIM, pe_W + (size_t)l * PEDIM * DIM,
                    pe_b + (size_t)l * DIM, attn_e + (size_t)l * DIM,
                    edge_emb + (size_t)l * 9 * DIM,
                    Btg + (size_t)l * DIM * KPAD, b2 + l * DIM, et + l * 16);
    } else {
        for (int i = threadIdx.x; i < 2 * NGSC * 256; i += 256) gs[i] = 0.f;
    }
}

// ---------------- fused (BN+residual) + MFMA GEMM + hl/hr ----------------
// MODE 0: A-rows from fp32 X. MODE 1: BN(bf16 OPREV) + fp32 XPREV. MODE 2:
// BN(bf16 OPREV) + bf16 XPREV. MODE 1/2 write bf16 XNEXT.
template<int MODE>
__global__ __launch_bounds__(256) void k_gemm(
    const void* __restrict__ OPREV, const void* __restrict__ XPREV,
    const float* __restrict__ gsrc, const float* __restrict__ gamma,
    const float* __restrict__ beta, unsigned short* __restrict__ XNEXT,
    const unsigned short* __restrict__ PEb, const unsigned short* __restrict__ Btg,
    const float* __restrict__ b2, const float* __restrict__ attn_l,
    const float* __restrict__ attn_r,
    unsigned short* __restrict__ H, float* __restrict__ HL, float* __restrict__ HR) {
    __shared__ unsigned short Bls[DIM * KPAD];   // 51.2 KB
    __shared__ float smu[DIM], ssc[DIM], sbt[DIM];
    const int tid = threadIdx.x;
    const int row0 = blockIdx.x * 64;
    const int w = tid >> 6, l = tid & 63;
    const int c = l & 15;     // A-row-in-tile / B-col / D-col
    const int g = l >> 4;     // k-subgroup / D-row-group
    const int row = row0 + w * 16 + c;
    const bool ok = row < NNODES;

    // issue A-source loads early
    float4 oxf[4][2], xpf[4][2];
    int4 oxb[4], xpb[4];
    #pragma unroll
    for (int s = 0; s < 4; ++s) {
        const int col0 = g * 8 + s * 32;
        const float4 z = {0.f, 0.f, 0.f, 0.f};
        if (MODE == 0) {
            oxf[s][0] = z; oxf[s][1] = z;
            if (ok) {
                const float4* op = (const float4*)&((const float*)OPREV)[((size_t)row << 7) + col0];
                oxf[s][0] = op[0]; oxf[s][1] = op[1];
            }
        } else {
            oxb[s] = make_int4(0, 0, 0, 0);
            if (ok) oxb[s] = *(const int4*)&((const unsigned short*)OPREV)[((size_t)row << 7) + col0];
            if (MODE == 1) {
                xpf[s][0] = z; xpf[s][1] = z;
                if (ok) {
                    const float4* xp = (const float4*)&((const float*)XPREV)[((size_t)row << 7) + col0];
                    xpf[s][0] = xp[0]; xpf[s][1] = xp[1];
                }
            } else {
                xpb[s] = make_int4(0, 0, 0, 0);
                if (ok) xpb[s] = *(const int4*)&((const unsigned short*)XPREV)[((size_t)row << 7) + col0];
            }
        }
    }
    int4 pe4 = {0, 0, 0, 0}, pe5 = {0, 0, 0, 0};
    if (ok) {
        const int4* pp = (const int4*)(PEb + (size_t)row * PEPAD);
        pe4 = pp[g];          // cols 128+g*8..+7
        pe5 = pp[4 + g];      // cols 160+g*8..+7
    }

    {   // stage B: 3200 int4, linear
        const int4* gb = (const int4*)Btg;
        int4* lb = (int4*)Bls;
        for (int i = tid; i < 3200; i += 256) gload_lds16(gb + i, lb + i);
    }
    if (MODE != 0 && tid < DIM) {   // block-local BN-stat reduce (16 spread copies)
        float s = 0.f, s2 = 0.f;
        #pragma unroll
        for (int q = 0; q < NGSC; ++q) {
            s += gsrc[q * 256 + tid];
            s2 += gsrc[q * 256 + 128 + tid];
        }
        const float mu = s * (1.f / NNODES);
        const float var = s2 * (1.f / NNODES) - mu * mu;
        smu[tid] = mu;
        ssc[tid] = gamma[tid] * rsqrtf(var + 1e-5f);
        sbt[tid] = beta[tid];
    }
    __syncthreads();

    // build A fragments (and write bf16 XNEXT for MODE 1/2)
    bf16x8 af[6];
    #pragma unroll
    for (int s = 0; s < 4; ++s) {
        const int col0 = g * 8 + s * 32;
        float xn[8];
        if (MODE == 0) {
            xn[0] = oxf[s][0].x; xn[1] = oxf[s][0].y; xn[2] = oxf[s][0].z; xn[3] = oxf[s][0].w;
            xn[4] = oxf[s][1].x; xn[5] = oxf[s][1].y; xn[6] = oxf[s][1].z; xn[7] = oxf[s][1].w;
        } else {
            const unsigned int u0 = (unsigned)oxb[s].x, u1 = (unsigned)oxb[s].y;
            const unsigned int u2 = (unsigned)oxb[s].z, u3 = (unsigned)oxb[s].w;
            float ov[8];
            ov[0] = __uint_as_float(u0 << 16); ov[1] = __uint_as_float(u0 & 0xFFFF0000u);
            ov[2] = __uint_as_float(u1 << 16); ov[3] = __uint_as_float(u1 & 0xFFFF0000u);
            ov[4] = __uint_as_float(u2 << 16); ov[5] = __uint_as_float(u2 & 0xFFFF0000u);
            ov[6] = __uint_as_float(u3 << 16); ov[7] = __uint_as_float(u3 & 0xFFFF0000u);
            float xv[8];
            if (MODE == 1) {
                xv[0] = xpf[s][0].x; xv[1] = xpf[s][0].y; xv[2] = xpf[s][0].z; xv[3] = xpf[s][0].w;
                xv[4] = xpf[s][1].x; xv[5] = xpf[s][1].y; xv[6] = xpf[s][1].z; xv[7] = xpf[s][1].w;
            } else {
                const unsigned int p0 = (unsigned)xpb[s].x, p1 = (unsigned)xpb[s].y;
                const unsigned int p2 = (unsigned)xpb[s].z, p3 = (unsigned)xpb[s].w;
                xv[0] = __uint_as_float(p0 << 16); xv[1] = __uint_as_float(p0 & 0xFFFF0000u);
                xv[2] = __uint_as_float(p1 << 16); xv[3] = __uint_as_float(p1 & 0xFFFF0000u);
                xv[4] = __uint_as_float(p2 << 16); xv[5] = __uint_as_float(p2 & 0xFFFF0000u);
                xv[6] = __uint_as_float(p3 << 16); xv[7] = __uint_as_float(p3 & 0xFFFF0000u);
            }
            const float4 mu0 = *(const float4*)&smu[col0], mu1 = *(const float4*)&smu[col0 + 4];
            const float4 sc0 = *(const float4*)&ssc[col0], sc1 = *(const float4*)&ssc[col0 + 4];
            const float4 bt0 = *(const float4*)&sbt[col0], bt1 = *(const float4*)&sbt[col0 + 4];
            xn[0] = (ov[0] - mu0.x) * sc0.x + bt0.x + xv[0];
            xn[1] = (ov[1] - mu0.y) * sc0.y + bt0.y + xv[1];
            xn[2] = (ov[2] - mu0.z) * sc0.z + bt0.z + xv[2];
            xn[3] = (ov[3] - mu0.w) * sc0.w + bt0.w + xv[3];
            xn[4] = (ov[4] - mu1.x) * sc1.x + bt1.x + xv[4];
            xn[5] = (ov[5] - mu1.y) * sc1.y + bt1.y + xv[5];
            xn[6] = (ov[6] - mu1.z) * sc1.z + bt1.z + xv[6];
            xn[7] = (ov[7] - mu1.w) * sc1.w + bt1.w + xv[7];
        }
        int4 pk;
        pk.x = (int)pack2(xn[0], xn[1]); pk.y = (int)pack2(xn[2], xn[3]);
        pk.z = (int)pack2(xn[4], xn[5]); pk.w = (int)pack2(xn[6], xn[7]);
        if (MODE != 0 && ok)
            *(int4*)&XNEXT[((size_t)row << 7) + col0] = pk;
        af[s] = *(const bf16x8*)&pk;
    }
    af[4] = *(const bf16x8*)&pe4;
    af[5] = *(const bf16x8*)&pe5;

    f32x4 zero4 = {0.f, 0.f, 0.f, 0.f};
    f32x4 acc[8];
    #pragma unroll
    for (int t = 0; t < 8; ++t) acc[t] = zero4;

    #pragma unroll
    for (int t = 0; t < 8; ++t) {
        const unsigned short* bRow = Bls + (size_t)(t * 16 + c) * KPAD + g * 8;
        #pragma unroll
        for (int s = 0; s < 6; ++s)
            acc[t] = __builtin_amdgcn_mfma_f32_16x16x32_bf16(af[s], *(const bf16x8*)(bRow + s * 32), acc[t], 0, 0, 0);
    }

    float b2v[8], alv[8], arv[8];
    #pragma unroll
    for (int t = 0; t < 8; ++t) {
        b2v[t] = b2[t * 16 + c];
        alv[t] = attn_l[t * 16 + c];
        arv[t] = attn_r[t * 16 + c];
    }
    #pragma unroll
    for (int t = 0; t < 8; ++t)
        #pragma unroll
        for (int j = 0; j < 4; ++j) acc[t][j] += b2v[t];

    #pragma unroll
    for (int j = 0; j < 4; ++j) {
        float sl = 0.f, sr = 0.f;
        #pragma unroll
        for (int t = 0; t < 8; ++t) { sl = fmaf(acc[t][j], alv[t], sl); sr = fmaf(acc[t][j], arv[t], sr); }
        #pragma unroll
        for (int m = 1; m < 16; m <<= 1) {
            sl += __shfl_xor(sl, m, 64);
            sr += __shfl_xor(sr, m, 64);
        }
        const int grow = row0 + w * 16 + g * 4 + j;
        if (grow < NNODES && c == 0) { HL[grow] = sl; HR[grow] = sr; }
    }

    // repack D tile -> bf16 via LDS (reuse Bls), then coalesced store
    __syncthreads();
    unsigned short* Hls = Bls;
    #pragma unroll
    for (int t = 0; t < 8; ++t)
        #pragma unroll
        for (int j = 0; j < 4; ++j)
            Hls[(w * 16 + g * 4 + j) * HSTR + t * 16 + c] = f2b(acc[t][j]);
    __syncthreads();
    #pragma unroll
    for (int kb = 0; kb < 4; ++kb) {
        const int idx = tid + kb * 256;         // 0..1023
        const int r = idx >> 4, kc = idx & 15;
        const int grow = row0 + r;
        if (grow < NNODES) {
            const int4 v = *(const int4*)(Hls + r * HSTR + kc * 8);
            ((int4*)(H + ((size_t)grow << 7)))[kc] = v;
        }
    }
}

// ---------------- per-node softmax + aggregation (one wave per node) ----------------
// 4 edge-groups x 16 lanes (lane owns 8 cols); 4-slot unroll = 16 edges/iter.
// FINAL=0: OUT(bf16) = agg + bias. FINAL=1: OUT(fp32 d_out, nontemporal) = agg + bias + bf16 xprev.
template<int FINAL>
__global__ __launch_bounds__(256) void k_agg(
    const int* __restrict__ offs, const int* __restrict__ csr,
    const float* __restrict__ HL, const float* __restrict__ HR,
    const float* __restrict__ et, const unsigned short* __restrict__ H,
    const float* __restrict__ bias, const unsigned short* __restrict__ xprev,
    void* __restrict__ OUTv) {
    const int lane = threadIdx.x & 63;
    const int node = blockIdx.x * 4 + (threadIdx.x >> 6);   // grid exact
    const int off0 = offs[node];
    const int deg = offs[node + 1] - off0;

    const float hri = HR[node];
    float myA = 0.f;
    int myE = 0;          // init 0 -> invalid slots broadcast a safe, valid row id
    float mx = -1e30f;
    for (int j = lane; j < deg; j += 64) {
        const int en = csr[off0 + j];
        float al = HL[en & 0xFFFF] + hri + et[en >> 16];
        al = al > 0.f ? al : 0.2f * al;
        if (j < 64) { myA = al; myE = en & 0xFFFF; }
        mx = fmaxf(mx, al);
    }
    #pragma unroll
    for (int m = 1; m < 64; m <<= 1) mx = fmaxf(mx, __shfl_xor(mx, m, 64));

    float s = 0.f, wv = 0.f;
    const bool small = deg <= 64;
    if (small) {
        wv = (lane < deg) ? __expf(myA - mx) : 0.f;
        s = wv;
    } else {
        for (int j = lane; j < deg; j += 64) {
            const int en = csr[off0 + j];
            float al = HL[en & 0xFFFF] + hri + et[en >> 16];
            al = al > 0.f ? al : 0.2f * al;
            s += __expf(al - mx);
        }
    }
    #pragma unroll
    for (int m = 1; m < 64; m <<= 1) s += __shfl_xor(s, m, 64);
    const float invd = (deg > 0) ? 1.f / s : 0.f;
    wv *= invd;

    const int eg = lane >> 4, c = lane & 15;   // group 0..3, col chunk: cols c*8..c*8+7
    float a[8];
    #pragma unroll
    for (int t = 0; t < 8; ++t) a[t] = 0.f;

    if (small) {
        for (int jb = 0; jb < deg; jb += 16) {
            float wl[4];
            int sl[4];
            #pragma unroll
            for (int u = 0; u < 4; ++u) {
                const int j = jb + eg + u * 4;
                wl[u] = __shfl(wv, j & 63, 64);
                sl[u] = __shfl(myE, j & 63, 64);
                if (j >= deg) wl[u] = 0.f;
            }
            int4 hv0 = *(const int4*)(H + ((size_t)sl[0] << 7) + (c << 3));
            int4 hv1 = *(const int4*)(H + ((size_t)sl[1] << 7) + (c << 3));
            int4 hv2 = *(const int4*)(H + ((size_t)sl[2] << 7) + (c << 3));
            int4 hv3 = *(const int4*)(H + ((size_t)sl[3] << 7) + (c << 3));
            const int4 hvv[4] = {hv0, hv1, hv2, hv3};
            #pragma unroll
            for (int u = 0; u < 4; ++u) {
                const unsigned int ux = (unsigned)hvv[u].x, uy = (unsigned)hvv[u].y;
                const unsigned int uz = (unsigned)hvv[u].z, uw = (unsigned)hvv[u].w;
                const float wg = wl[u];
                a[0] = fmaf(wg, __uint_as_float(ux << 16), a[0]);
                a[1] = fmaf(wg, __uint_as_float(ux & 0xFFFF0000u), a[1]);
                a[2] = fmaf(wg, __uint_as_float(uy << 16), a[2]);
                a[3] = fmaf(wg, __uint_as_float(uy & 0xFFFF0000u), a[3]);
                a[4] = fmaf(wg, __uint_as_float(uz << 16), a[4]);
                a[5] = fmaf(wg, __uint_as_float(uz & 0xFFFF0000u), a[5]);
                a[6] = fmaf(wg, __uint_as_float(uw << 16), a[6]);
                a[7] = fmaf(wg, __uint_as_float(uw & 0xFFFF0000u), a[7]);
            }
        }
    } else {
        for (int jb = 0; jb < deg; jb += 8) {
            float wl[2];
            int sl[2];
            #pragma unroll
            for (int u = 0; u < 2; ++u) {
                const int j = jb + eg + u * 4;
                wl[u] = 0.f; sl[u] = 0;
                if (j < deg) {
                    const int en = csr[off0 + j];
                    sl[u] = en & 0xFFFF;
                    float al = HL[sl[u]] + hri + et[en >> 16];
                    al = al > 0.f ? al : 0.2f * al;
                    wl[u] = __expf(al - mx) * invd;
                }
            }
            int4 hv0 = *(const int4*)(H + ((size_t)sl[0] << 7) + (c << 3));
            int4 hv1 = *(const int4*)(H + ((size_t)sl[1] << 7) + (c << 3));
            const int4 hvv[2] = {hv0, hv1};
            #pragma unroll
            for (int u = 0; u < 2; ++u) {
                const unsigned int ux = (unsigned)hvv[u].x, uy = (unsigned)hvv[u].y;
                const unsigned int uz = (unsigned)hvv[u].z, uw = (unsigned)hvv[u].w;
                const float wg = wl[u];
                a[0] = fmaf(wg, __uint_as_float(ux << 16), a[0]);
                a[1] = fmaf(wg, __uint_as_float(ux & 0xFFFF0000u), a[1]);
                a[2] = fmaf(wg, __uint_as_float(uy << 16), a[2]);
                a[3] = fmaf(wg, __uint_as_float(uy & 0xFFFF0000u), a[3]);
                a[4] = fmaf(wg, __uint_as_float(uz << 16), a[4]);
                a[5] = fmaf(wg, __uint_as_float(uz & 0xFFFF0000u), a[5]);
                a[6] = fmaf(wg, __uint_as_float(uw << 16), a[6]);
                a[7] = fmaf(wg, __uint_as_float(uw & 0xFFFF0000u), a[7]);
            }
        }
    }

    // cross-group reduce: 2 levels (bits 4,5)
    #pragma unroll
    for (int m = 16; m < 64; m <<= 1)
        #pragma unroll
        for (int t = 0; t < 8; ++t) a[t] += __shfl_xor(a[t], m, 64);

    if (eg == 0) {
        float o[8];
        const float* bp = bias + (c << 3);
        #pragma unroll
        for (int t = 0; t < 8; ++t) o[t] = a[t] + bp[t];
        if (FINAL) {
            float* OUT = (float*)OUTv;
            const int4 xb = *(const int4*)(xprev + ((size_t)node << 7) + (c << 3));
            const unsigned int p0 = (unsigned)xb.x, p1 = (unsigned)xb.y;
            const unsigned int p2 = (unsigned)xb.z, p3 = (unsigned)xb.w;
            o[0] += __uint_as_float(p0 << 16); o[1] += __uint_as_float(p0 & 0xFFFF0000u);
            o[2] += __uint_as_float(p1 << 16); o[3] += __uint_as_float(p1 & 0xFFFF0000u);
            o[4] += __uint_as_float(p2 << 16); o[5] += __uint_as_float(p2 & 0xFFFF0000u);
            o[6] += __uint_as_float(p3 << 16); o[7] += __uint_as_float(p3 & 0xFFFF0000u);
            float* op = OUT + ((size_t)node << 7) + (c << 3);
            f32x4 o0 = {o[0], o[1], o[2], o[3]};
            f32x4 o1 = {o[4], o[5], o[6], o[7]};
            __builtin_nontemporal_store(o0, (f32x4*)op);      // d_out: never re-read on device
            __builtin_nontemporal_store(o1, (f32x4*)(op + 4));
        } else {
            unsigned short* OUT = (unsigned short*)OUTv;
            int4 pk;
            pk.x = (int)pack2(o[0], o[1]); pk.y = (int)pack2(o[2], o[3]);
            pk.z = (int)pack2(o[4], o[5]); pk.w = (int)pack2(o[6], o[7]);
            *(int4*)(OUT + ((size_t)node << 7) + (c << 3)) = pk;
        }
    }
}

// ---------------- BN stats on bf16 obuf (196 blocks, 16-copy spread gs) ----------------
__global__ __launch_bounds__(256) void k_bnstats(
    const unsigned short* __restrict__ OUT, float* __restrict__ gs) {
    __shared__ float lsl[256], lsh[256], l2l[256], l2h[256];
    const int c2 = threadIdx.x & 63;   // uint col = bf16 cols {2c2, 2c2+1}
    const int q  = threadIdx.x >> 6;   // 0..3 row split
    const int rend = min(NNODES, (int)(blockIdx.x * 256 + 256));
    const unsigned int* U = (const unsigned int*)OUT;
    float sl = 0.f, sh = 0.f, s2l = 0.f, s2h = 0.f;
    for (int r = blockIdx.x * 256 + q; r < rend; r += 4) {
        const unsigned int u = U[(size_t)r * 64 + c2];
        const float lo = __uint_as_float(u << 16);
        const float hi = __uint_as_float(u & 0xFFFF0000u);
        sl += lo; sh += hi;
        s2l = fmaf(lo, lo, s2l); s2h = fmaf(hi, hi, s2h);
    }
    lsl[threadIdx.x] = sl; lsh[threadIdx.x] = sh;
    l2l[threadIdx.x] = s2l; l2h[threadIdx.x] = s2h;
    __syncthreads();
    if (threadIdx.x < 64) {
        float a0 = 0.f, a1 = 0.f, a2 = 0.f, a3 = 0.f;
        #pragma unroll
        for (int k = 0; k < 4; ++k) {
            a0 += lsl[k * 64 + c2]; a1 += lsh[k * 64 + c2];
            a2 += l2l[k * 64 + c2]; a3 += l2h[k * 64 + c2];
        }
        const int qq = blockIdx.x & (NGSC - 1);
        atomicAdd(&gs[qq * 256 + 2 * c2], a0);
        atomicAdd(&gs[qq * 256 + 2 * c2 + 1], a1);
        atomicAdd(&gs[qq * 256 + 128 + 2 * c2], a2);
        atomicAdd(&gs[qq * 256 + 128 + 2 * c2 + 1], a3);
    }
}

// ---------------- host ----------------
extern "C" void kernel_launch(void* const* d_in, const int* in_sizes, int n_in,
                              void* d_out, int out_size, void* d_ws, size_t ws_size,
                              hipStream_t stream) {
    const float* X_n      = (const float*)d_in[0];
    const float* PE       = (const float*)d_in[1];
    const int*   eidx     = (const int*)d_in[2];
    const int*   eattr    = (const int*)d_in[3];
    const float* edge_emb = (const float*)d_in[4];
    const float* pe_W     = (const float*)d_in[5];
    const float* pe_b     = (const float*)d_in[6];
    const float* lin_W    = (const float*)d_in[7];
    const float* attn_l   = (const float*)d_in[8];
    const float* attn_r   = (const float*)d_in[9];
    const float* attn_e   = (const float*)d_in[10];
    const float* bias     = (const float*)d_in[11];
    const float* bng      = (const float*)d_in[12];
    const float* bnb      = (const float*)d_in[13];

    if (ws_size < WS_NEED) return;

    char* ws = (char*)d_ws;
    unsigned short* x1    = (unsigned short*)(ws + OFF_X1);
    unsigned short* x2    = (unsigned short*)(ws + OFF_X2);
    unsigned short* obufb = (unsigned short*)(ws + OFF_O);
    unsigned short* hbuf  = (unsigned short*)(ws + OFF_H);
    unsigned short* PEb   = (unsigned short*)(ws + OFF_PEB);
    float* hl     = (float*)(ws + OFF_HL);
    float* hr     = (float*)(ws + OFF_HR);
    int*   offs   = (int*)(ws + OFF_OFFS);
    int*   cur    = (int*)(ws + OFF_CUR);
    int*   csr    = (int*)(ws + OFF_CSR);
    int*   tmp    = (int*)(ws + OFF_TMP);
    int*   bcur   = (int*)(ws + OFF_BCUR);
    unsigned short* Btg = (unsigned short*)(ws + OFF_BTG);
    float* b2     = (float*)(ws + OFF_B2);
    float* et     = (float*)(ws + OFF_ET);
    float* gs     = (float*)(ws + OFF_GS);   // gs + NGSC*256*b for boundary b
    int*   bsum   = (int*)(ws + OFF_BS);
    int*   bpre   = (int*)(ws + OFF_BP);

    const int* srcv = eidx;
    const int* dstv = eidx + NEDGES;

    hipLaunchKernelGGL(k_zero_int, dim3(256), dim3(256), 0, stream, cur, NNODES);
    hipLaunchKernelGGL(k_count, dim3(1024), dim3(256), 0, stream, dstv, cur);
    hipLaunchKernelGGL(k_scan1, dim3(NSB), dim3(256), 0, stream, cur, bsum);
    hipLaunchKernelGGL(k_scan2, dim3(1), dim3(256), 0, stream, bsum, bpre, offs);
    hipLaunchKernelGGL(k_scan3, dim3(NSB), dim3(256), 0, stream, cur, bpre, offs, cur, bcur);
    hipLaunchKernelGGL(k_fillA, dim3(1024), dim3(256), 0, stream, srcv, dstv, eattr, bcur, tmp);
    hipLaunchKernelGGL(k_fillB, dim3(NBUCK), dim3(256), 0, stream, offs, tmp, cur, csr);
    hipLaunchKernelGGL(k_pack, dim3(NPEB + 3 * 101 + 1), dim3(256), 0, stream,
                       PE, lin_W, pe_W, pe_b, attn_e, edge_emb, PEb, Btg, b2, et, gs);

    const int NGB = (NNODES + 63) / 64;
    // layer 0
    hipLaunchKernelGGL((k_gemm<0>), dim3(NGB), dim3(256), 0, stream,
                       (const void*)X_n, (const void*)nullptr, (const float*)nullptr,
                       (const float*)nullptr, (const float*)nullptr, (unsigned short*)nullptr,
                       PEb, Btg, b2, attn_l, attn_r, hbuf, hl, hr);
    hipLaunchKernelGGL((k_agg<0>), dim3(NNODES / 4), dim3(256), 0, stream,
                       offs, csr, hl, hr, et, hbuf, bias, (const unsigned short*)nullptr, (void*)obufb);
    hipLaunchKernelGGL(k_bnstats, dim3(NSB), dim3(256), 0, stream, obufb, gs);
    // layer 1 (BN boundary 0 fused into GEMM; residual source = fp32 X_n)
    hipLaunchKernelGGL((k_gemm<1>), dim3(NGB), dim3(256), 0, stream,
                       (const void*)obufb, (const void*)X_n, gs, bng, bnb, x1,
                       PEb, Btg + (size_t)DIM * KPAD, b2 + DIM, attn_l + DIM, attn_r + DIM,
                       hbuf, hl, hr);
    hipLaunchKernelGGL((k_agg<0>), dim3(NNODES / 4), dim3(256), 0, stream,
                       offs, csr, hl, hr, et + 16, hbuf, bias + DIM, (const unsigned short*)nullptr, (void*)obufb);
    hipLaunchKernelGGL(k_bnstats, dim3(NSB), dim3(256), 0, stream, obufb, gs + NGSC * 256);
    // layer 2 (BN boundary 1 fused into GEMM; residual source = bf16 x1)
    hipLaunchKernelGGL((k_gemm<2>), dim3(NGB), dim3(256), 0, stream,
                       (const void*)obufb, (const void*)x1, gs + NGSC * 256, bng + DIM, bnb + DIM, x2,
                       PEb, Btg + 2 * (size_t)DIM * KPAD, b2 + 2 * DIM, attn_l + 2 * DIM, attn_r + 2 * DIM,
                       hbuf, hl, hr);
    hipLaunchKernelGGL((k_agg<1>), dim3(NNODES / 4), dim3(256), 0, stream,
                       offs, csr, hl, hr, et + 32, hbuf, bias + 2 * DIM, x2,
                       (void*)d_out);
}